// Round 1
// 533.802 us; speedup vs baseline: 1.0617x; 1.0617x over previous
//
#include <hip/hip_runtime.h>
#include <stdint.h>

#define B_  32
#define N_  576
#define C_  768
#define H_  12
#define HD_ 64
#define M_  (B_*N_)    // 18432
#define C3_ (3*C_)     // 2304
#define K_  768

typedef __attribute__((ext_vector_type(8))) short short8;
typedef __attribute__((ext_vector_type(4))) float f32x4;

__device__ __forceinline__ uint  f2u(float x){ return __float_as_uint(x); }
__device__ __forceinline__ float u2f(uint x){ return __uint_as_float(x); }

// explicit DMA/LDS drain (attn kernel; merges with compiler waits)
__device__ __forceinline__ void drain_all() {
  asm volatile("s_waitcnt vmcnt(0) lgkmcnt(0)" ::: "memory");
}

// truncation split: hi = top16(a), lo = bf16(a - hi); combined rel err <= 2^-16
__device__ __forceinline__ void split1(float a, ushort& h, ushort& l) {
  uint b0 = f2u(a);
  h = (ushort)(b0 >> 16);
  l = (ushort)(f2u(a - u2f(b0 & 0xffff0000u)) >> 16);
}
__device__ __forceinline__ void split2(float a, float b, uint& hw, uint& lw) {
  uint b0 = f2u(a), b1 = f2u(b);
  uint t0 = b0 & 0xffff0000u, t1 = b1 & 0xffff0000u;
  hw = (b0 >> 16) | t1;
  lw = (f2u(a - u2f(t0)) >> 16) | (f2u(b - u2f(t1)) & 0xffff0000u);
}
// bf16 round-to-nearest-even
__device__ __forceinline__ ushort bf16rn(float x) {
  uint u = f2u(x);
  return (ushort)((u + 0x7fffu + ((u >> 16) & 1u)) >> 16);
}

// async global->LDS 16B DMA; LDS dest is wave-uniform base + lane*16
__device__ __forceinline__ void gload16(const ushort* g, ushort* l) {
  auto gp = (const __attribute__((address_space(1))) uint*)(g);
  auto lp = reinterpret_cast<__attribute__((address_space(3))) uint*>(
              reinterpret_cast<uintptr_t>(l));
  __builtin_amdgcn_global_load_lds(gp, lp, 16, 0, 0);
}

// swizzled 64x64 bf16 tile: logical (row, chunk c of 8 ushorts) at slot
// row*8 + (c ^ (row&7)); DMA writes linear slots carrying the matching chunk.
__device__ __forceinline__ short8 frag_read(const ushort* t, int row, int c) {
  return *(const short8*)&t[((row << 3) + (c ^ (row & 7))) << 3];
}

// elementwise f32 -> (hi,lo) bf16 planes
__global__ __launch_bounds__(256)
void split_f32(const float* __restrict__ src, ushort* __restrict__ hi,
               ushort* __restrict__ lo, int n4) {
  int i = blockIdx.x * 256 + threadIdx.x;
  if (i >= n4) return;
  float4 a = ((const float4*)src)[i];
  uint h0, l0, h1, l1;
  split2(a.x, a.y, h0, l0); split2(a.z, a.w, h1, l1);
  ((uint2*)hi)[i] = make_uint2(h0, h1);
  ((uint2*)lo)[i] = make_uint2(l0, l1);
}

// ---------------------------------------------------------------------------
// Split-bf16 MFMA GEMM, pipelined (T3+T4): 256x256 tile, BK=32, 8 waves
// (2Mx4N, 128x64 per wave), double-buffered LDS (2 x 4 planes x 16KB =
// 128KB), counted vmcnt (never 0 in main loop), raw s_barrier, setprio
// around MFMA clusters, bijective XCD swizzle. 3 MFMA products per k-frag.
// EPI 0: scatter q/k (split, q pre-scaled 0.125) + v (single bf16, transposed)
// EPI 1: f32 output + bias (proj)
// ---------------------------------------------------------------------------
template<int EPI>
__global__ __launch_bounds__(512, 2)
void gemm_mfma(const ushort* __restrict__ Ah, const ushort* __restrict__ Al,
               const ushort* __restrict__ Bh, const ushort* __restrict__ Bl,
               const float* __restrict__ bias, float* __restrict__ Cf,
               ushort* __restrict__ QpH, ushort* __restrict__ QpL,
               ushort* __restrict__ KpH, ushort* __restrict__ KpL,
               ushort* __restrict__ Vt, int Nout) {
  // [dbuf][plane: AH,AL,BH,BL][256 rows x 4 chunk-slots x 8 ushorts]
  __shared__ ushort S[2][4][8192];

  const int tid  = threadIdx.x;
  const int lane = tid & 63, wave = tid >> 6;
  const int ln15 = lane & 15, cq = lane >> 4;
  const int wrow = (wave >> 2) << 7, wcol = (wave & 3) << 6;

  // XCD-aware bijective swizzle: both grids (648, 216 wgs) are %8 == 0
  const int nbx  = gridDim.x;
  const int nwg  = nbx * gridDim.y;
  const int orig = blockIdx.y * nbx + blockIdx.x;
  const int swz  = (orig & 7) * (nwg >> 3) + (orig >> 3);
  const int m0 = (swz / nbx) << 8, n0 = (swz % nbx) << 8;

  int aslot[8], bslot[4];
#pragma unroll
  for (int i = 0; i < 8; i++) {
    int r = wrow + (i << 4) + ln15;
    aslot[i] = (r << 2) + (cq ^ ((r >> 1) & 3));
  }
#pragma unroll
  for (int j = 0; j < 4; j++) {
    int r = wcol + (j << 4) + ln15;
    bslot[j] = (r << 2) + (cq ^ ((r >> 1) & 3));
  }

  // staging: per wave 2 parts x (A hi/lo + B hi/lo) 1KB DMAs = 8 per tile
  int ldso[2];
  const ushort *pAh[2], *pAl[2], *pBh[2], *pBl[2];
#pragma unroll
  for (int p = 0; p < 2; p++) {
    const int bs = ((wave << 1) + p) << 6;
    const int s = bs + lane, row = s >> 2, c = (s & 3) ^ ((row >> 1) & 3);
    ldso[p] = bs << 3;
    pAh[p] = Ah + (size_t)(m0 + row) * K_ + (c << 3);
    pAl[p] = Al + (size_t)(m0 + row) * K_ + (c << 3);
    pBh[p] = Bh + (size_t)(n0 + row) * K_ + (c << 3);
    pBl[p] = Bl + (size_t)(n0 + row) * K_ + (c << 3);
  }

  auto issue8 = [&](int d, int k0) {
#pragma unroll
    for (int p = 0; p < 2; p++) {
      gload16(pAh[p] + k0, &S[d][0][ldso[p]]);
      gload16(pAl[p] + k0, &S[d][1][ldso[p]]);
      gload16(pBh[p] + k0, &S[d][2][ldso[p]]);
      gload16(pBl[p] + k0, &S[d][3][ldso[p]]);
    }
  };

  f32x4 acc[8][4];
#pragma unroll
  for (int i = 0; i < 8; i++)
#pragma unroll
    for (int j = 0; j < 4; j++) acc[i][j] = (f32x4)0.f;

  // prologue: tiles 0 and 1 in flight; wait for tile 0 (vmcnt(8))
  issue8(0, 0);
  issue8(1, 32);
  asm volatile("s_waitcnt vmcnt(8)" ::: "memory");
  __builtin_amdgcn_s_barrier();
  __builtin_amdgcn_sched_barrier(0);

  constexpr int NT = K_ / 32;   // 24
  for (int t = 0; t < NT; ++t) {
    const int cur = t & 1;
    const ushort* AHs = &S[cur][0][0];
    const ushort* ALs = &S[cur][1][0];
    const ushort* BHs = &S[cur][2][0];
    const ushort* BLs = &S[cur][3][0];

    // 4 quadrant phases: bounded frag registers, setprio'd MFMA clusters
#pragma unroll
    for (int qm = 0; qm < 2; ++qm)
#pragma unroll
      for (int qn = 0; qn < 2; ++qn) {
        short8 ah[4], al[4], bh[2], bl[2];
#pragma unroll
        for (int ii = 0; ii < 4; ++ii) {
          ah[ii] = *(const short8*)&AHs[aslot[(qm << 2) + ii] << 3];
          al[ii] = *(const short8*)&ALs[aslot[(qm << 2) + ii] << 3];
        }
#pragma unroll
        for (int jj = 0; jj < 2; ++jj) {
          bh[jj] = *(const short8*)&BHs[bslot[(qn << 1) + jj] << 3];
          bl[jj] = *(const short8*)&BLs[bslot[(qn << 1) + jj] << 3];
        }
        __builtin_amdgcn_s_setprio(1);
#pragma unroll
        for (int jj = 0; jj < 2; ++jj)
#pragma unroll
          for (int ii = 0; ii < 4; ++ii) {
            const int i = (qm << 2) + ii, j = (qn << 1) + jj;
            acc[i][j] = __builtin_amdgcn_mfma_f32_16x16x32_bf16(ah[ii], bh[jj], acc[i][j], 0, 0, 0);
            acc[i][j] = __builtin_amdgcn_mfma_f32_16x16x32_bf16(ah[ii], bl[jj], acc[i][j], 0, 0, 0);
            acc[i][j] = __builtin_amdgcn_mfma_f32_16x16x32_bf16(al[ii], bh[jj], acc[i][j], 0, 0, 0);
          }
        __builtin_amdgcn_s_setprio(0);
      }

    if (t == NT - 1) break;
    // step boundary: reads of S[cur] done -> barrier -> prefetch t+2 into
    // S[cur] -> wait tile t+1 landed (8 newest stay in flight) -> barrier
    asm volatile("s_waitcnt lgkmcnt(0)" ::: "memory");
    __builtin_amdgcn_sched_barrier(0);
    __builtin_amdgcn_s_barrier();
    if (t + 2 < NT) {
      issue8(cur, (t + 2) << 5);
      asm volatile("s_waitcnt vmcnt(8)" ::: "memory");
    } else {
      asm volatile("s_waitcnt vmcnt(0)" ::: "memory");
    }
    __builtin_amdgcn_s_barrier();
    __builtin_amdgcn_sched_barrier(0);
  }

  // epilogue: C/D layout col=lane&15, row=(lane>>4)*4+reg
  if (EPI == 1) {
#pragma unroll
    for (int j = 0; j < 4; j++) {
      const int col = n0 + wcol + (j << 4) + ln15;
      const float bv = bias[col];
#pragma unroll
      for (int i = 0; i < 8; i++)
#pragma unroll
        for (int r = 0; r < 4; r++) {
          const int row_g = m0 + wrow + (i << 4) + (cq << 2) + r;
          Cf[(size_t)row_g * Nout + col] = acc[i][j][r] + bv;
        }
    }
  } else {
#pragma unroll
    for (int j = 0; j < 4; j++) {
      const int col = n0 + wcol + (j << 4) + ln15;
      const int which = col / 768;              // block-uniform (768 = 3*256)
      const int hh = (col % 768) >> 6;
      const int dd = col & 63;
      const float bv = bias[col];
      const float scale = (which == 0) ? 0.125f : 1.f;
#pragma unroll
      for (int i = 0; i < 8; i++) {
        const int base_row = m0 + wrow + (i << 4) + (cq << 2);
        const int b = base_row / 576;           // constant across r (4 | 576)
        const int n = base_row - b * 576;
        const size_t bh = (size_t)b * H_ + hh;
        if (which == 2) {                       // V -> single bf16, (b,h,d,n)
          ushort hv[4];
#pragma unroll
          for (int r = 0; r < 4; r++) hv[r] = bf16rn(acc[i][j][r] + bv);
          const size_t dst = (bh * 64 + dd) * 576 + n;
          *(ushort4*)&Vt[dst] = make_ushort4(hv[0], hv[1], hv[2], hv[3]);
        } else {                                // Q/K -> split planes (b,h,n,d)
          ushort* dh = which ? KpH : QpH;
          ushort* dl = which ? KpL : QpL;
#pragma unroll
          for (int r = 0; r < 4; r++) {
            ushort hs, ls;
            split1((acc[i][j][r] + bv) * scale, hs, ls);
            const size_t dst = (bh * 576 + n + r) * 64 + dd;
            dh[dst] = hs; dl[dst] = ls;
          }
        }
      }
    }
  }
}

// ---------------------------------------------------------------------------
// MFMA flash attention, block-causal. Q/K split (3-product S), V+P plain bf16
// (1-product PV). P stays wave-private -> lgkm wait only. p_s padded +8KB to
// hold LDS at 56KB -> 2 blocks/CU (round-3 proven occupancy regime).
// ---------------------------------------------------------------------------
__global__ __launch_bounds__(256)
void attn_mfma(const ushort* __restrict__ QH, const ushort* __restrict__ QL,
               const ushort* __restrict__ KHp, const ushort* __restrict__ KLp,
               const ushort* __restrict__ Vp,
               ushort* __restrict__ OH, ushort* __restrict__ OL) {
  __shared__ ushort qh_s[64*64], ql_s[64*64];
  __shared__ ushort kh_s[64*64], kl_s[64*64];
  __shared__ ushort vh_s[64*64];
  __shared__ ushort p_s[64*64 + 4096];     // +8KB pad: keep 2 blocks/CU

  const int tid  = threadIdx.x;
  const int lane = tid & 63, wave = tid >> 6;
  const int ln15 = lane & 15, quad = lane >> 4;
  const int qt = blockIdx.x;                  // 0..8
  const int bh = blockIdx.y;                  // 0..383
  const int q0 = qt << 6;
  const size_t pbase = (size_t)bh * (576 * 64);

  // stage Q (hi/lo)
#pragma unroll
  for (int p = 0; p < 2; p++) {
    const int bs = ((wave << 1) + p) << 6;
    const int s = bs + lane, row = s >> 3, c = (s & 7) ^ (row & 7);
    const size_t off = pbase + (size_t)(q0 + row) * 64 + (c << 3);
    gload16(QH + off, &qh_s[bs << 3]);
    gload16(QL + off, &ql_s[bs << 3]);
  }

  int bi_q[4];
#pragma unroll
  for (int r = 0; r < 4; r++) {
    const int p = q0 + (wave << 4) + (quad << 2) + r;
    bi_q[r] = (p / 96) * 6 + ((p % 24) >> 2);
  }
  const int qmax = 6 * ((qt * 64 + 159) / 96) - 1;
  const int qmin = 6 * ((2 * qt) / 3);

  f32x4 oacc[4];
#pragma unroll
  for (int dt = 0; dt < 4; dt++) oacc[dt] = (f32x4)0.f;
  float mrun[4], lrun[4];
#pragma unroll
  for (int r = 0; r < 4; r++) { mrun[r] = -1e30f; lrun[r] = 0.f; }

#pragma unroll
  for (int kt = 0; kt < 9; ++kt) {
    const int tmink = 6 * ((2 * kt) / 3);
    const int tmaxk = 6 * ((kt * 64 + 159) / 96) - 1;
    if (tmink > qmax) continue;               // future block-tile: skip
    const bool nomask = (tmaxk <= qmin);

    drain_all();
    __syncthreads();                          // prev K/V reads done
#pragma unroll
    for (int p = 0; p < 2; p++) {
      const int bs = ((wave << 1) + p) << 6;
      const int s = bs + lane, row = s >> 3, c = (s & 7) ^ (row & 7);
      const size_t koff = pbase + (size_t)((kt << 6) + row) * 64 + (c << 3);
      gload16(KHp + koff, &kh_s[bs << 3]);
      gload16(KLp + koff, &kl_s[bs << 3]);
      const size_t voff = pbase + (size_t)row * 576 + (kt << 6) + (c << 3);
      gload16(Vp + voff, &vh_s[bs << 3]);
    }
    drain_all();                              // DMAs drained before barrier
    __syncthreads();

    // S = Q K^T  (pre-scaled by 0.125 via Q)
    f32x4 sacc[4];
#pragma unroll
    for (int j = 0; j < 4; j++) sacc[j] = (f32x4)0.f;
#pragma unroll
    for (int s2 = 0; s2 < 2; ++s2) {
      const short8 aqh = frag_read(qh_s, (wave << 4) + ln15, (s2 << 2) + quad);
      const short8 aql = frag_read(ql_s, (wave << 4) + ln15, (s2 << 2) + quad);
#pragma unroll
      for (int j = 0; j < 4; j++) {
        const short8 bkh = frag_read(kh_s, (j << 4) + ln15, (s2 << 2) + quad);
        const short8 bkl = frag_read(kl_s, (j << 4) + ln15, (s2 << 2) + quad);
        sacc[j] = __builtin_amdgcn_mfma_f32_16x16x32_bf16(aqh, bkh, sacc[j], 0, 0, 0);
        sacc[j] = __builtin_amdgcn_mfma_f32_16x16x32_bf16(aqh, bkl, sacc[j], 0, 0, 0);
        sacc[j] = __builtin_amdgcn_mfma_f32_16x16x32_bf16(aql, bkh, sacc[j], 0, 0, 0);
      }
    }

    float sv[4][4];
#pragma unroll
    for (int j = 0; j < 4; j++)
#pragma unroll
      for (int r = 0; r < 4; r++) sv[j][r] = sacc[j][r];

    if (!nomask) {
      int bi_k[4];
#pragma unroll
      for (int j = 0; j < 4; j++) {
        const int p = (kt << 6) + (j << 4) + ln15;
        bi_k[j] = (p / 96) * 6 + ((p % 24) >> 2);
      }
#pragma unroll
      for (int j = 0; j < 4; j++)
#pragma unroll
        for (int r = 0; r < 4; r++)
          if (bi_k[j] > bi_q[r]) sv[j][r] = -1e30f;
    }

    // online softmax; row r lives in the 16 lanes of this quad
#pragma unroll
    for (int r = 0; r < 4; r++) {
      float rm = fmaxf(fmaxf(sv[0][r], sv[1][r]), fmaxf(sv[2][r], sv[3][r]));
      rm = fmaxf(rm, __shfl_xor(rm, 1));
      rm = fmaxf(rm, __shfl_xor(rm, 2));
      rm = fmaxf(rm, __shfl_xor(rm, 4));
      rm = fmaxf(rm, __shfl_xor(rm, 8));
      const float mnew  = fmaxf(mrun[r], rm);
      const float alpha = __expf(mrun[r] - mnew);
      float rs = 0.f;
#pragma unroll
      for (int j = 0; j < 4; j++) {
        const float pj = __expf(sv[j][r] - mnew);
        sv[j][r] = pj; rs += pj;
      }
      rs += __shfl_xor(rs, 1);
      rs += __shfl_xor(rs, 2);
      rs += __shfl_xor(rs, 4);
      rs += __shfl_xor(rs, 8);
      lrun[r] = lrun[r] * alpha + rs;
      mrun[r] = mnew;
#pragma unroll
      for (int dt = 0; dt < 4; dt++) oacc[dt][r] *= alpha;
    }

    // P (bf16) -> own rows of p_s; wave-private, only a lgkm wait needed
#pragma unroll
    for (int j = 0; j < 4; j++)
#pragma unroll
      for (int r = 0; r < 4; r++) {
        const int row = (wave << 4) + (quad << 2) + r;
        const int col = (j << 4) + ln15;
        const int c = col >> 3, e = col & 7;
        p_s[(((row << 3) + (c ^ (row & 7))) << 3) + e] = bf16rn(sv[j][r]);
      }
    asm volatile("s_waitcnt lgkmcnt(0)" ::: "memory");

    // O += P V
#pragma unroll
    for (int s2 = 0; s2 < 2; ++s2) {
      const short8 pf = frag_read(p_s, (wave << 4) + ln15, (s2 << 2) + quad);
#pragma unroll
      for (int dt = 0; dt < 4; dt++) {
        const short8 bvh = frag_read(vh_s, (dt << 4) + ln15, (s2 << 2) + quad);
        oacc[dt] = __builtin_amdgcn_mfma_f32_16x16x32_bf16(pf, bvh, oacc[dt], 0, 0, 0);
      }
    }
  }

  // normalize + write split planes, token-major (M, C) for the proj GEMM
  const int b = bh / H_, h = bh % H_;
#pragma unroll
  for (int r = 0; r < 4; r++) {
    const float inv = 1.f / lrun[r];
    const int row_g = b * 576 + q0 + (wave << 4) + (quad << 2) + r;
#pragma unroll
    for (int dt = 0; dt < 4; dt++) {
      const float v = oacc[dt][r] * inv;
      ushort hs, ls;
      split1(v, hs, ls);
      const size_t dst = (size_t)row_g * 768 + h * 64 + (dt << 4) + ln15;
      OH[dst] = hs; OL[dst] = ls;
    }
  }
}

// ---------------------------------------------------------------------------
extern "C" void kernel_launch(void* const* d_in, const int* in_sizes, int n_in,
                              void* d_out, int out_size, void* d_ws, size_t ws_size,
                              hipStream_t stream) {
  const float* x      = (const float*)d_in[0];
  const float* qkv_w  = (const float*)d_in[1];
  const float* qkv_b  = (const float*)d_in[2];
  const float* proj_w = (const float*)d_in[3];
  const float* proj_b = (const float*)d_in[4];
  float* out = (float*)d_out;

  // ws layout (peak 205 MB < proven 226.5 MB):
  // [Qp hi/lo][Kp hi/lo][Vt] planes 0-4; [XH][XL] planes 5-6 (x split, dead
  // after QKV -> overlaid by attn-out AH/AL); [QW hi/lo 7.1MB at 7nP, dead
  // after QKV -> overlaid by PW hi/lo (split AFTER attention, round-3 order)].
  ushort* ws = (ushort*)d_ws;
  const size_t nP = (size_t)B_ * H_ * 576 * 64;   // 14,155,776 (= M_*C_)
  ushort* QpH = ws + 0 * nP;
  ushort* QpL = ws + 1 * nP;
  ushort* KpH = ws + 2 * nP;
  ushort* KpL = ws + 3 * nP;
  ushort* Vt  = ws + 4 * nP;
  ushort* XH  = ws + 5 * nP;                      // x split planes
  ushort* XL  = ws + 6 * nP;
  ushort* AH  = ws + 5 * nP;                      // attn out (overlay X planes)
  ushort* AL  = ws + 6 * nP;
  ushort* QWH = ws + 7 * nP;                      // qkv_w split
  ushort* QWL = QWH + (size_t)C3_ * C_;
  ushort* PWH = ws + 7 * nP;                      // proj_w split (overlay QW)
  ushort* PWL = PWH + (size_t)C_ * C_;

  // 1) split x and qkv_w
  split_f32<<<(M_*K_/4 + 255)/256, 256, 0, stream>>>(x, XH, XL, M_*K_/4);
  split_f32<<<(C3_*C_/4 + 255)/256, 256, 0, stream>>>(qkv_w, QWH, QWL, C3_*C_/4);

  // 2) qkv GEMM (pipelined 256^2), epilogue scatters q/k/v planes
  gemm_mfma<0><<<dim3(C3_/256, M_/256), 512, 0, stream>>>(
      XH, XL, QWH, QWL, qkv_b, nullptr, QpH, QpL, KpH, KpL, Vt, C3_);

  // 3) attention (X planes now dead; writes AH/AL over them)
  attn_mfma<<<dim3(9, B_*H_), 256, 0, stream>>>(
      QpH, QpL, KpH, KpL, Vt, AH, AL);

  // 4) split proj_w (QW region dead after QKV GEMM) — round-3 order
  split_f32<<<(C_*C_/4 + 255)/256, 256, 0, stream>>>(proj_w, PWH, PWL, C_*C_/4);

  // 5) proj GEMM -> f32 out
  gemm_mfma<1><<<dim3(C_/256, M_/256), 512, 0, stream>>>(
      AH, AL, PWH, PWL, proj_b, out,
      nullptr, nullptr, nullptr, nullptr, nullptr, C_);
}

// Round 2
// 527.196 us; speedup vs baseline: 1.0750x; 1.0125x over previous
//
#include <hip/hip_runtime.h>
#include <stdint.h>

#define B_  32
#define N_  576
#define C_  768
#define H_  12
#define HD_ 64
#define M_  (B_*N_)    // 18432
#define C3_ (3*C_)     // 2304
#define K_  768

typedef __attribute__((ext_vector_type(8))) short short8;
typedef __attribute__((ext_vector_type(4))) float f32x4;

__device__ __forceinline__ uint  f2u(float x){ return __float_as_uint(x); }
__device__ __forceinline__ float u2f(uint x){ return __uint_as_float(x); }

// explicit DMA/LDS drain (attn kernel; merges with compiler waits)
__device__ __forceinline__ void drain_all() {
  asm volatile("s_waitcnt vmcnt(0) lgkmcnt(0)" ::: "memory");
}

// truncation split: hi = top16(a), lo = bf16(a - hi); combined rel err <= 2^-16
__device__ __forceinline__ void split1(float a, ushort& h, ushort& l) {
  uint b0 = f2u(a);
  h = (ushort)(b0 >> 16);
  l = (ushort)(f2u(a - u2f(b0 & 0xffff0000u)) >> 16);
}
__device__ __forceinline__ void split2(float a, float b, uint& hw, uint& lw) {
  uint b0 = f2u(a), b1 = f2u(b);
  uint t0 = b0 & 0xffff0000u, t1 = b1 & 0xffff0000u;
  hw = (b0 >> 16) | t1;
  lw = (f2u(a - u2f(t0)) >> 16) | (f2u(b - u2f(t1)) & 0xffff0000u);
}
// bf16 round-to-nearest-even
__device__ __forceinline__ ushort bf16rn(float x) {
  uint u = f2u(x);
  return (ushort)((u + 0x7fffu + ((u >> 16) & 1u)) >> 16);
}

// async global->LDS 16B DMA; LDS dest is wave-uniform base + lane*16
__device__ __forceinline__ void gload16(const ushort* g, ushort* l) {
  auto gp = (const __attribute__((address_space(1))) uint*)(g);
  auto lp = reinterpret_cast<__attribute__((address_space(3))) uint*>(
              reinterpret_cast<uintptr_t>(l));
  __builtin_amdgcn_global_load_lds(gp, lp, 16, 0, 0);
}

// swizzled 64x64 bf16 tile: logical (row, chunk c of 8 ushorts) at slot
// row*8 + (c ^ (row&7)); DMA writes linear slots carrying the matching chunk.
__device__ __forceinline__ short8 frag_read(const ushort* t, int row, int c) {
  return *(const short8*)&t[((row << 3) + (c ^ (row & 7))) << 3];
}

// elementwise f32 -> (hi,lo) bf16 planes
__global__ __launch_bounds__(256)
void split_f32(const float* __restrict__ src, ushort* __restrict__ hi,
               ushort* __restrict__ lo, int n4) {
  int i = blockIdx.x * 256 + threadIdx.x;
  if (i >= n4) return;
  float4 a = ((const float4*)src)[i];
  uint h0, l0, h1, l1;
  split2(a.x, a.y, h0, l0); split2(a.z, a.w, h1, l1);
  ((uint2*)hi)[i] = make_uint2(h0, h1);
  ((uint2*)lo)[i] = make_uint2(l0, l1);
}

// ---------------------------------------------------------------------------
// Split-bf16 MFMA GEMM, pipelined: 256x256 tile, BK=32, 8 waves (2Mx4N,
// 128x64 per wave), double-buffered LDS (128KB), counted vmcnt (never 0 in
// main loop), raw s_barrier, setprio around MFMA clusters, XCD swizzle.
// LDS-read-minimal inner loop: 24 ds_read_b128 per K-step (B frags held
// across the step, each A/B fragment read exactly once) vs 48 in round-1
// quadrant phasing -> LDS BW demand halved (was the 33%-MfmaUtil ceiling).
// EPI 0: scatter q/k (split, q pre-scaled 0.125) + v (single bf16, transposed)
// EPI 1: f32 output + bias (proj)
// ---------------------------------------------------------------------------
template<int EPI>
__global__ __launch_bounds__(512, 2)
void gemm_mfma(const ushort* __restrict__ Ah, const ushort* __restrict__ Al,
               const ushort* __restrict__ Bh, const ushort* __restrict__ Bl,
               const float* __restrict__ bias, float* __restrict__ Cf,
               ushort* __restrict__ QpH, ushort* __restrict__ QpL,
               ushort* __restrict__ KpH, ushort* __restrict__ KpL,
               ushort* __restrict__ Vt, int Nout) {
  // [dbuf][plane: AH,AL,BH,BL][256 rows x 4 chunk-slots x 8 ushorts]
  __shared__ ushort S[2][4][8192];

  const int tid  = threadIdx.x;
  const int lane = tid & 63, wave = tid >> 6;
  const int ln15 = lane & 15, cq = lane >> 4;
  const int wrow = (wave >> 2) << 7, wcol = (wave & 3) << 6;

  // XCD-aware bijective swizzle: both grids (648, 216 wgs) are %8 == 0
  const int nbx  = gridDim.x;
  const int nwg  = nbx * gridDim.y;
  const int orig = blockIdx.y * nbx + blockIdx.x;
  const int swz  = (orig & 7) * (nwg >> 3) + (orig >> 3);
  const int m0 = (swz / nbx) << 8, n0 = (swz % nbx) << 8;

  int aslot[8], bslot[4];
#pragma unroll
  for (int i = 0; i < 8; i++) {
    int r = wrow + (i << 4) + ln15;
    aslot[i] = (r << 2) + (cq ^ ((r >> 1) & 3));
  }
#pragma unroll
  for (int j = 0; j < 4; j++) {
    int r = wcol + (j << 4) + ln15;
    bslot[j] = (r << 2) + (cq ^ ((r >> 1) & 3));
  }

  // staging: per wave 2 parts x (A hi/lo + B hi/lo) 1KB DMAs = 8 per tile
  int ldso[2];
  const ushort *pAh[2], *pAl[2], *pBh[2], *pBl[2];
#pragma unroll
  for (int p = 0; p < 2; p++) {
    const int bs = ((wave << 1) + p) << 6;
    const int s = bs + lane, row = s >> 2, c = (s & 3) ^ ((row >> 1) & 3);
    ldso[p] = bs << 3;
    pAh[p] = Ah + (size_t)(m0 + row) * K_ + (c << 3);
    pAl[p] = Al + (size_t)(m0 + row) * K_ + (c << 3);
    pBh[p] = Bh + (size_t)(n0 + row) * K_ + (c << 3);
    pBl[p] = Bl + (size_t)(n0 + row) * K_ + (c << 3);
  }

  auto issue8 = [&](int d, int k0) {
#pragma unroll
    for (int p = 0; p < 2; p++) {
      gload16(pAh[p] + k0, &S[d][0][ldso[p]]);
      gload16(pAl[p] + k0, &S[d][1][ldso[p]]);
      gload16(pBh[p] + k0, &S[d][2][ldso[p]]);
      gload16(pBl[p] + k0, &S[d][3][ldso[p]]);
    }
  };

  f32x4 acc[8][4];
#pragma unroll
  for (int i = 0; i < 8; i++)
#pragma unroll
    for (int j = 0; j < 4; j++) acc[i][j] = (f32x4)0.f;

  // prologue: tiles 0 and 1 in flight; wait for tile 0 (vmcnt(8))
  issue8(0, 0);
  issue8(1, 32);
  asm volatile("s_waitcnt vmcnt(8)" ::: "memory");
  __builtin_amdgcn_s_barrier();
  __builtin_amdgcn_sched_barrier(0);

  constexpr int NT = K_ / 32;   // 24
  for (int t = 0; t < NT; ++t) {
    const int cur = t & 1;
    const ushort* AHs = &S[cur][0][0];
    const ushort* ALs = &S[cur][1][0];
    const ushort* BHs = &S[cur][2][0];
    const ushort* BLs = &S[cur][3][0];

    // all 8 B fragments held live for the whole K-step (read once)
    short8 bh[4], bl[4];
#pragma unroll
    for (int j = 0; j < 4; j++) {
      bh[j] = *(const short8*)&BHs[bslot[j] << 3];
      bl[j] = *(const short8*)&BLs[bslot[j] << 3];
    }

    // two A-quadrant phases; each A fragment read once
#pragma unroll
    for (int qm = 0; qm < 2; ++qm) {
      short8 ah[4], al[4];
#pragma unroll
      for (int ii = 0; ii < 4; ++ii) {
        ah[ii] = *(const short8*)&AHs[aslot[(qm << 2) + ii] << 3];
        al[ii] = *(const short8*)&ALs[aslot[(qm << 2) + ii] << 3];
      }
      __builtin_amdgcn_s_setprio(1);
#pragma unroll
      for (int j = 0; j < 4; ++j)
#pragma unroll
        for (int ii = 0; ii < 4; ++ii) {
          const int i = (qm << 2) + ii;
          acc[i][j] = __builtin_amdgcn_mfma_f32_16x16x32_bf16(ah[ii], bh[j], acc[i][j], 0, 0, 0);
          acc[i][j] = __builtin_amdgcn_mfma_f32_16x16x32_bf16(ah[ii], bl[j], acc[i][j], 0, 0, 0);
          acc[i][j] = __builtin_amdgcn_mfma_f32_16x16x32_bf16(al[ii], bh[j], acc[i][j], 0, 0, 0);
        }
      __builtin_amdgcn_s_setprio(0);
    }

    if (t == NT - 1) break;
    // step boundary: reads of S[cur] done -> barrier -> prefetch t+2 into
    // S[cur] -> wait tile t+1 landed (8 newest stay in flight) -> barrier
    asm volatile("s_waitcnt lgkmcnt(0)" ::: "memory");
    __builtin_amdgcn_sched_barrier(0);
    __builtin_amdgcn_s_barrier();
    if (t + 2 < NT) {
      issue8(cur, (t + 2) << 5);
      asm volatile("s_waitcnt vmcnt(8)" ::: "memory");
    } else {
      asm volatile("s_waitcnt vmcnt(0)" ::: "memory");
    }
    __builtin_amdgcn_s_barrier();
    __builtin_amdgcn_sched_barrier(0);
  }

  // epilogue: C/D layout col=lane&15, row=(lane>>4)*4+reg
  if (EPI == 1) {
#pragma unroll
    for (int j = 0; j < 4; j++) {
      const int col = n0 + wcol + (j << 4) + ln15;
      const float bv = bias[col];
#pragma unroll
      for (int i = 0; i < 8; i++)
#pragma unroll
        for (int r = 0; r < 4; r++) {
          const int row_g = m0 + wrow + (i << 4) + (cq << 2) + r;
          Cf[(size_t)row_g * Nout + col] = acc[i][j][r] + bv;
        }
    }
  } else {
#pragma unroll
    for (int j = 0; j < 4; j++) {
      const int col = n0 + wcol + (j << 4) + ln15;
      const int which = col / 768;              // block-uniform (768 = 3*256)
      const int hh = (col % 768) >> 6;
      const int dd = col & 63;
      const float bv = bias[col];
      const float scale = (which == 0) ? 0.125f : 1.f;
#pragma unroll
      for (int i = 0; i < 8; i++) {
        const int base_row = m0 + wrow + (i << 4) + (cq << 2);
        const int b = base_row / 576;           // constant across r (4 | 576)
        const int n = base_row - b * 576;
        const size_t bh = (size_t)b * H_ + hh;
        if (which == 2) {                       // V -> single bf16, (b,h,d,n)
          ushort hv[4];
#pragma unroll
          for (int r = 0; r < 4; r++) hv[r] = bf16rn(acc[i][j][r] + bv);
          const size_t dst = (bh * 64 + dd) * 576 + n;
          *(ushort4*)&Vt[dst] = make_ushort4(hv[0], hv[1], hv[2], hv[3]);
        } else {                                // Q/K -> split planes (b,h,n,d)
          ushort* dh = which ? KpH : QpH;
          ushort* dl = which ? KpL : QpL;
#pragma unroll
          for (int r = 0; r < 4; r++) {
            ushort hs, ls;
            split1((acc[i][j][r] + bv) * scale, hs, ls);
            const size_t dst = (bh * 576 + n + r) * 64 + dd;
            dh[dst] = hs; dl[dst] = ls;
          }
        }
      }
    }
  }
}

// ---------------------------------------------------------------------------
// MFMA flash attention, block-causal. Q/K split (3-product S), V+P plain bf16
// (1-product PV). P stays wave-private -> lgkm wait only. p_s padded +8KB to
// hold LDS at 56KB -> 2 blocks/CU (round-3 proven occupancy regime).
// ---------------------------------------------------------------------------
__global__ __launch_bounds__(256)
void attn_mfma(const ushort* __restrict__ QH, const ushort* __restrict__ QL,
               const ushort* __restrict__ KHp, const ushort* __restrict__ KLp,
               const ushort* __restrict__ Vp,
               ushort* __restrict__ OH, ushort* __restrict__ OL) {
  __shared__ ushort qh_s[64*64], ql_s[64*64];
  __shared__ ushort kh_s[64*64], kl_s[64*64];
  __shared__ ushort vh_s[64*64];
  __shared__ ushort p_s[64*64 + 4096];     // +8KB pad: keep 2 blocks/CU

  const int tid  = threadIdx.x;
  const int lane = tid & 63, wave = tid >> 6;
  const int ln15 = lane & 15, quad = lane >> 4;
  const int qt = blockIdx.x;                  // 0..8
  const int bh = blockIdx.y;                  // 0..383
  const int q0 = qt << 6;
  const size_t pbase = (size_t)bh * (576 * 64);

  // stage Q (hi/lo)
#pragma unroll
  for (int p = 0; p < 2; p++) {
    const int bs = ((wave << 1) + p) << 6;
    const int s = bs + lane, row = s >> 3, c = (s & 7) ^ (row & 7);
    const size_t off = pbase + (size_t)(q0 + row) * 64 + (c << 3);
    gload16(QH + off, &qh_s[bs << 3]);
    gload16(QL + off, &ql_s[bs << 3]);
  }

  int bi_q[4];
#pragma unroll
  for (int r = 0; r < 4; r++) {
    const int p = q0 + (wave << 4) + (quad << 2) + r;
    bi_q[r] = (p / 96) * 6 + ((p % 24) >> 2);
  }
  const int qmax = 6 * ((qt * 64 + 159) / 96) - 1;
  const int qmin = 6 * ((2 * qt) / 3);

  f32x4 oacc[4];
#pragma unroll
  for (int dt = 0; dt < 4; dt++) oacc[dt] = (f32x4)0.f;
  float mrun[4], lrun[4];
#pragma unroll
  for (int r = 0; r < 4; r++) { mrun[r] = -1e30f; lrun[r] = 0.f; }

#pragma unroll
  for (int kt = 0; kt < 9; ++kt) {
    const int tmink = 6 * ((2 * kt) / 3);
    const int tmaxk = 6 * ((kt * 64 + 159) / 96) - 1;
    if (tmink > qmax) continue;               // future block-tile: skip
    const bool nomask = (tmaxk <= qmin);

    drain_all();
    __syncthreads();                          // prev K/V reads done
#pragma unroll
    for (int p = 0; p < 2; p++) {
      const int bs = ((wave << 1) + p) << 6;
      const int s = bs + lane, row = s >> 3, c = (s & 7) ^ (row & 7);
      const size_t koff = pbase + (size_t)((kt << 6) + row) * 64 + (c << 3);
      gload16(KHp + koff, &kh_s[bs << 3]);
      gload16(KLp + koff, &kl_s[bs << 3]);
      const size_t voff = pbase + (size_t)row * 576 + (kt << 6) + (c << 3);
      gload16(Vp + voff, &vh_s[bs << 3]);
    }
    drain_all();                              // DMAs drained before barrier
    __syncthreads();

    // S = Q K^T  (pre-scaled by 0.125 via Q)
    f32x4 sacc[4];
#pragma unroll
    for (int j = 0; j < 4; j++) sacc[j] = (f32x4)0.f;
#pragma unroll
    for (int s2 = 0; s2 < 2; ++s2) {
      const short8 aqh = frag_read(qh_s, (wave << 4) + ln15, (s2 << 2) + quad);
      const short8 aql = frag_read(ql_s, (wave << 4) + ln15, (s2 << 2) + quad);
#pragma unroll
      for (int j = 0; j < 4; j++) {
        const short8 bkh = frag_read(kh_s, (j << 4) + ln15, (s2 << 2) + quad);
        const short8 bkl = frag_read(kl_s, (j << 4) + ln15, (s2 << 2) + quad);
        sacc[j] = __builtin_amdgcn_mfma_f32_16x16x32_bf16(aqh, bkh, sacc[j], 0, 0, 0);
        sacc[j] = __builtin_amdgcn_mfma_f32_16x16x32_bf16(aqh, bkl, sacc[j], 0, 0, 0);
        sacc[j] = __builtin_amdgcn_mfma_f32_16x16x32_bf16(aql, bkh, sacc[j], 0, 0, 0);
      }
    }

    float sv[4][4];
#pragma unroll
    for (int j = 0; j < 4; j++)
#pragma unroll
      for (int r = 0; r < 4; r++) sv[j][r] = sacc[j][r];

    if (!nomask) {
      int bi_k[4];
#pragma unroll
      for (int j = 0; j < 4; j++) {
        const int p = (kt << 6) + (j << 4) + ln15;
        bi_k[j] = (p / 96) * 6 + ((p % 24) >> 2);
      }
#pragma unroll
      for (int j = 0; j < 4; j++)
#pragma unroll
        for (int r = 0; r < 4; r++)
          if (bi_k[j] > bi_q[r]) sv[j][r] = -1e30f;
    }

    // online softmax; row r lives in the 16 lanes of this quad
#pragma unroll
    for (int r = 0; r < 4; r++) {
      float rm = fmaxf(fmaxf(sv[0][r], sv[1][r]), fmaxf(sv[2][r], sv[3][r]));
      rm = fmaxf(rm, __shfl_xor(rm, 1));
      rm = fmaxf(rm, __shfl_xor(rm, 2));
      rm = fmaxf(rm, __shfl_xor(rm, 4));
      rm = fmaxf(rm, __shfl_xor(rm, 8));
      const float mnew  = fmaxf(mrun[r], rm);
      const float alpha = __expf(mrun[r] - mnew);
      float rs = 0.f;
#pragma unroll
      for (int j = 0; j < 4; j++) {
        const float pj = __expf(sv[j][r] - mnew);
        sv[j][r] = pj; rs += pj;
      }
      rs += __shfl_xor(rs, 1);
      rs += __shfl_xor(rs, 2);
      rs += __shfl_xor(rs, 4);
      rs += __shfl_xor(rs, 8);
      lrun[r] = lrun[r] * alpha + rs;
      mrun[r] = mnew;
#pragma unroll
      for (int dt = 0; dt < 4; dt++) oacc[dt][r] *= alpha;
    }

    // P (bf16) -> own rows of p_s; wave-private, only a lgkm wait needed
#pragma unroll
    for (int j = 0; j < 4; j++)
#pragma unroll
      for (int r = 0; r < 4; r++) {
        const int row = (wave << 4) + (quad << 2) + r;
        const int col = (j << 4) + ln15;
        const int c = col >> 3, e = col & 7;
        p_s[(((row << 3) + (c ^ (row & 7))) << 3) + e] = bf16rn(sv[j][r]);
      }
    asm volatile("s_waitcnt lgkmcnt(0)" ::: "memory");

    // O += P V
#pragma unroll
    for (int s2 = 0; s2 < 2; ++s2) {
      const short8 pf = frag_read(p_s, (wave << 4) + ln15, (s2 << 2) + quad);
#pragma unroll
      for (int dt = 0; dt < 4; dt++) {
        const short8 bvh = frag_read(vh_s, (dt << 4) + ln15, (s2 << 2) + quad);
        oacc[dt] = __builtin_amdgcn_mfma_f32_16x16x32_bf16(pf, bvh, oacc[dt], 0, 0, 0);
      }
    }
  }

  // normalize + write split planes, token-major (M, C) for the proj GEMM
  const int b = bh / H_, h = bh % H_;
#pragma unroll
  for (int r = 0; r < 4; r++) {
    const float inv = 1.f / lrun[r];
    const int row_g = b * 576 + q0 + (wave << 4) + (quad << 2) + r;
#pragma unroll
    for (int dt = 0; dt < 4; dt++) {
      const float v = oacc[dt][r] * inv;
      ushort hs, ls;
      split1(v, hs, ls);
      const size_t dst = (size_t)row_g * 768 + h * 64 + (dt << 4) + ln15;
      OH[dst] = hs; OL[dst] = ls;
    }
  }
}

// ---------------------------------------------------------------------------
extern "C" void kernel_launch(void* const* d_in, const int* in_sizes, int n_in,
                              void* d_out, int out_size, void* d_ws, size_t ws_size,
                              hipStream_t stream) {
  const float* x      = (const float*)d_in[0];
  const float* qkv_w  = (const float*)d_in[1];
  const float* qkv_b  = (const float*)d_in[2];
  const float* proj_w = (const float*)d_in[3];
  const float* proj_b = (const float*)d_in[4];
  float* out = (float*)d_out;

  // ws layout (peak 205 MB < proven 226.5 MB):
  // [Qp hi/lo][Kp hi/lo][Vt] planes 0-4; [XH][XL] planes 5-6 (x split, dead
  // after QKV -> overlaid by attn-out AH/AL); [QW hi/lo 7.1MB at 7nP, dead
  // after QKV -> overlaid by PW hi/lo (split AFTER attention, round-3 order)].
  ushort* ws = (ushort*)d_ws;
  const size_t nP = (size_t)B_ * H_ * 576 * 64;   // 14,155,776 (= M_*C_)
  ushort* QpH = ws + 0 * nP;
  ushort* QpL = ws + 1 * nP;
  ushort* KpH = ws + 2 * nP;
  ushort* KpL = ws + 3 * nP;
  ushort* Vt  = ws + 4 * nP;
  ushort* XH  = ws + 5 * nP;                      // x split planes
  ushort* XL  = ws + 6 * nP;
  ushort* AH  = ws + 5 * nP;                      // attn out (overlay X planes)
  ushort* AL  = ws + 6 * nP;
  ushort* QWH = ws + 7 * nP;                      // qkv_w split
  ushort* QWL = QWH + (size_t)C3_ * C_;
  ushort* PWH = ws + 7 * nP;                      // proj_w split (overlay QW)
  ushort* PWL = PWH + (size_t)C_ * C_;

  // 1) split x and qkv_w
  split_f32<<<(M_*K_/4 + 255)/256, 256, 0, stream>>>(x, XH, XL, M_*K_/4);
  split_f32<<<(C3_*C_/4 + 255)/256, 256, 0, stream>>>(qkv_w, QWH, QWL, C3_*C_/4);

  // 2) qkv GEMM (pipelined 256^2), epilogue scatters q/k/v planes
  gemm_mfma<0><<<dim3(C3_/256, M_/256), 512, 0, stream>>>(
      XH, XL, QWH, QWL, qkv_b, nullptr, QpH, QpL, KpH, KpL, Vt, C3_);

  // 3) attention (X planes now dead; writes AH/AL over them)
  attn_mfma<<<dim3(9, B_*H_), 256, 0, stream>>>(
      QpH, QpL, KpH, KpL, Vt, AH, AL);

  // 4) split proj_w (QW region dead after QKV GEMM) — round-3 order
  split_f32<<<(C_*C_/4 + 255)/256, 256, 0, stream>>>(proj_w, PWH, PWL, C_*C_/4);

  // 5) proj GEMM -> f32 out
  gemm_mfma<1><<<dim3(C_/256, M_/256), 512, 0, stream>>>(
      AH, AL, PWH, PWL, proj_b, out,
      nullptr, nullptr, nullptr, nullptr, nullptr, C_);
}